// Round 10
// baseline (483.015 us; speedup 1.0000x reference)
//
#include <hip/hip_runtime.h>

typedef unsigned short u16;
typedef unsigned int   u32;
typedef unsigned long long u64;
typedef __attribute__((ext_vector_type(8))) short bf16x8;
typedef __attribute__((ext_vector_type(4))) float f32x4;

#define MFMA16(A,B,C) __builtin_amdgcn_mfma_f32_16x16x32_bf16(A,B,C,0,0,0)
#define MFMAF8(A,B,C) __builtin_amdgcn_mfma_f32_16x16x32_fp8_fp8(A,B,C,0,0,0)

__device__ __forceinline__ u16 f2bf(float f){
    u32 u = __float_as_uint(f);
    u += 0x7fffu + ((u >> 16) & 1u);
    return (u16)(u >> 16);
}
__device__ __forceinline__ u32 pk2(float lo, float hi){
    return (u32)f2bf(lo) | ((u32)f2bf(hi) << 16);
}
__device__ __forceinline__ float upk(u32 u, int hi){
    return __uint_as_float(hi ? (u & 0xffff0000u) : (u << 16));
}
__device__ __forceinline__ float bf2f(u16 v){
    return __uint_as_float(((u32)v) << 16);
}
__device__ __forceinline__ float fast_tanh(float p){
    float e2 = __expf(2.f * p);
    return 1.f - __fdividef(2.f, e2 + 1.f);
}
__device__ __forceinline__ void gload16(const u16* g, u16* l){
    __builtin_amdgcn_global_load_lds((const __attribute__((address_space(1))) void*)g,
                                     (__attribute__((address_space(3))) void*)l, 16, 0, 0);
}

// ---------------- weight pre-pack kernel ----------------
// ws (u16 each 65536): [0]=W1 bf16, [1]=unused, [2]=W2 fp8 (64KB bytes, chunked),
//                      [3]=W2T bf16, [4]=Wc bf16
// Style A (32-col chunks, which 0/3/4): q = c(4b)|ks(2b)|t(1b)|l(6b)|j(3b)
//   k = 32*ks + (l>>4)*8 + j ; n = 32*c + 16*t + (l&15)
// fp8 W2 (which 2): byte q = lc(4b)|nt(3b)|lane(6b)|j(3b)
//   k = lc*32 + (lane>>4)*8 + j ; n = nt*16 + (lane&15)
__global__ __launch_bounds__(256) void pack_weights_kernel(
    const float* __restrict__ W1, const float* __restrict__ W2,
    const float* __restrict__ Wc, u16* __restrict__ wp)
{
    int p = blockIdx.x * 256 + threadIdx.x;     // 0 .. 5*65536-1
    int which = p >> 16;
    int q = p & 65535;
    if (which == 1) return;                     // region unused
    if (which == 2){
        int j = q & 7, lane = (q >> 3) & 63;
        int nt = (q >> 9) & 7, lc = (q >> 12) & 15;
        int k = lc * 32 + (lane >> 4) * 8 + j;
        int n = nt * 16 + (lane & 15);
        float v = W2[k * 128 + n];
        u32 b = (u32)__builtin_amdgcn_cvt_pk_fp8_f32(v, 0.f, 0, 0) & 0xffu;
        ((unsigned char*)(wp + 131072))[q] = (unsigned char)b;
        return;
    }
    int j = q & 7, l = (q >> 3) & 63, t = (q >> 9) & 1;
    int ks = (q >> 10) & 3, c = (q >> 12) & 15;
    int l15v = l & 15, l4v = l >> 4;
    int k = 32 * ks + l4v * 8 + j;
    int n = 32 * c + 16 * t + l15v;
    float v = (which == 0) ? W1[k * 512 + n] : (which == 3) ? W2[n * 128 + k] : Wc[k * 512 + n];
    wp[p] = f2bf(v);
}

// ---------------- fused CNF RK4: streamed W1+W2f8 pipeline, 2 blocks/CU ----------------
__global__ __launch_bounds__(512, 2) void cnf_mfma8_kernel(
    const float* __restrict__ x, const float* __restrict__ logpx,
    const float* __restrict__ cond, const float* __restrict__ e,
    const float* __restrict__ b1, const u16* __restrict__ wp,
    const float* __restrict__ bt, const float* __restrict__ b2,
    float* __restrict__ y_out, float* __restrict__ lp_out)
{
    __shared__ __align__(16) u16 s_w1[3][4096];            // 3x8KB W1 stream slots
    __shared__ __align__(16) unsigned char s_w2s[3][4096]; // 3x4KB W2-fp8 stream slots
    __shared__ __align__(16) u16 s_xx[4][16 * 136];        // per-pair xx transpose
    __shared__ __align__(16) unsigned char s_hh8[4][16 * 40]; // per-pair h (fp8, pad 32->40)
    __shared__ u32 s_xs[8][8][64];                         // per-wave xs state
    __shared__ u16 s_bt[512];
    __shared__ float s_b2[128];
    __shared__ float s_red[4][2][16];

    const int tid = threadIdx.x, wave = tid >> 6, lane = tid & 63;
    const int l15 = lane & 15, l4 = lane >> 4;
    const int pair = wave >> 1, half = wave & 1;
    const int rbase = blockIdx.x * 64 + pair * 16;
    const int wlt4 = __builtin_amdgcn_readfirstlane((wave < 4) ? 1 : 0);

    const u16* W1p  = wp;
    const u16* W2Tp = wp + 196608;
    const u16* Wcp  = wp + 262144;
    const unsigned char* W2f8p = (const unsigned char*)(wp + 131072);

    auto stage_chunk = [&](int slot, int cidx){
        gload16(W1p + cidx * 4096 + wave * 512 + lane * 8, &s_w1[slot][wave * 512 + lane * 8]);
        if (wave < 4)
            gload16((const u16*)(W2f8p + cidx * 4096 + wave * 1024 + lane * 16),
                    (u16*)&s_w2s[slot][wave * 1024 + lane * 16]);
    };

    s_bt[tid] = f2bf(bt[tid]);
    if (tid < 128) s_b2[tid] = b2[tid];

    u32 base_pk[16][2], q_pk[16][2];

    // ---- cond transpose -> cA frags; pass 1: base = cond@Wc + b1 ----
    {
        #pragma unroll
        for (int i = 0; i < 8; ++i){
            const int row = half * 8 + i;
            s_xx[pair][row * 136 + lane]      = f2bf(cond[(size_t)(rbase + row) * 128 + lane]);
            s_xx[pair][row * 136 + 64 + lane] = f2bf(cond[(size_t)(rbase + row) * 128 + 64 + lane]);
        }
        __syncthreads();
        bf16x8 cA[4];
        #pragma unroll
        for (int ks = 0; ks < 4; ++ks)
            cA[ks] = *(const bf16x8*)&s_xx[pair][l15 * 136 + ks * 32 + l4 * 8];
        __syncthreads();

        #pragma unroll 1
        for (int nc = 0; nc < 16; ++nc){
            gload16(Wcp + nc * 4096 + wave * 512 + lane * 8, &s_w1[0][wave * 512 + lane * 8]);
            __syncthreads();                     // drains vmcnt -> chunk landed
            f32x4 ab = {0.f, 0.f, 0.f, 0.f};
            #pragma unroll
            for (int ks = 0; ks < 4; ++ks)
                ab = MFMA16(cA[ks], *(const bf16x8*)&s_w1[0][(ks * 2 + half) * 512 + lane * 8], ab);
            const float b1v = b1[nc * 32 + half * 16 + l15];
            base_pk[nc][0] = pk2(ab[0] + b1v, ab[1] + b1v);
            base_pk[nc][1] = pk2(ab[2] + b1v, ab[3] + b1v);
            __syncthreads();                     // reads drained before next overwrite
        }
    }

    // ---- e transpose -> eA frags; pass 2: q = (e@W1) ⊙ (e@W2T) ----
    {
        #pragma unroll
        for (int i = 0; i < 8; ++i){
            const int row = half * 8 + i;
            s_xx[pair][row * 136 + lane]      = f2bf(e[(size_t)(rbase + row) * 128 + lane]);
            s_xx[pair][row * 136 + 64 + lane] = f2bf(e[(size_t)(rbase + row) * 128 + 64 + lane]);
        }
        __syncthreads();
        bf16x8 eA[4];
        #pragma unroll
        for (int ks = 0; ks < 4; ++ks)
            eA[ks] = *(const bf16x8*)&s_xx[pair][l15 * 136 + ks * 32 + l4 * 8];
        __syncthreads();

        #pragma unroll 1
        for (int nc = 0; nc < 16; ++nc){
            gload16(W1p  + nc * 4096 + wave * 512 + lane * 8, &s_w1[0][wave * 512 + lane * 8]);
            gload16(W2Tp + nc * 4096 + wave * 512 + lane * 8, &s_w1[1][wave * 512 + lane * 8]);
            __syncthreads();
            f32x4 ew = {0.f,0.f,0.f,0.f}, e2 = {0.f,0.f,0.f,0.f};
            #pragma unroll
            for (int ks = 0; ks < 4; ++ks){
                ew = MFMA16(eA[ks], *(const bf16x8*)&s_w1[0][(ks * 2 + half) * 512 + lane * 8], ew);
                e2 = MFMA16(eA[ks], *(const bf16x8*)&s_w1[1][(ks * 2 + half) * 512 + lane * 8], e2);
            }
            q_pk[nc][0] = pk2(ew[0] * e2[0], ew[1] * e2[1]);
            q_pk[nc][1] = pk2(ew[2] * e2[2], ew[3] * e2[3]);
            __syncthreads();
        }
    }

    // ---- x0 init: xs into per-wave LDS state; xn into pair xx area ----
    #pragma unroll
    for (int ntl = 0; ntl < 4; ++ntl)
        #pragma unroll
        for (int rr = 0; rr < 2; ++rr){
            const int row0 = rbase + l4 * 4 + 2 * rr;
            const int col = half * 64 + ntl * 16 + l15;
            const float a0 = x[(size_t)row0 * 128 + col];
            const float a1 = x[(size_t)(row0 + 1) * 128 + col];
            const u32 xp = pk2(a0, a1);
            s_xs[wave][ntl * 2 + rr][lane] = xp;
            s_xx[pair][(l4 * 4 + 2 * rr) * 136 + col]     = (u16)(xp & 0xffffu);
            s_xx[pair][(l4 * 4 + 2 * rr + 1) * 136 + col] = (u16)(xp >> 16);
        }

    // ---- prime pipeline: chunks 0,1,2 -> slots 0,1,2 ----
    #pragma unroll
    for (int c = 0; c < 3; ++c) stage_chunk(c, c);

    // ---- main RK4 loop: 16 stages x 16 chunks of 32 H-cols ----
    f32x4 acc[4];
    u32 dxc_pk[4][2];
    float divacc[4] = {0.f, 0.f, 0.f, 0.f};
    #pragma unroll
    for (int ntl = 0; ntl < 4; ++ntl){
        acc[ntl] = {0.f, 0.f, 0.f, 0.f};
        dxc_pk[ntl][0] = 0u; dxc_pk[ntl][1] = 0u;
    }
    bf16x8 xxA[4];

    #pragma unroll 1
    for (int st = 0; st < 16; ++st){
        const int stg = st & 3;
        const float tcur = 0.25f * (float)(st >> 2) + ((stg == 0) ? 0.f : (stg == 3) ? 0.25f : 0.125f);
        const float wcur = (stg == 1 || stg == 2) ? 2.f : 1.f;

        #pragma unroll 1
        for (int lc = 0; lc < 16; ++lc){
            const int c = st * 16 + lc;
            const int slot = c % 3;
            // chunk-top: chunk c landed (oldest in flight); all LDS writes visible
            if (wlt4) { asm volatile("s_waitcnt vmcnt(4) lgkmcnt(0)" ::: "memory"); }
            else      { asm volatile("s_waitcnt vmcnt(2) lgkmcnt(0)" ::: "memory"); }
            __builtin_amdgcn_sched_barrier(0);
            __builtin_amdgcn_s_barrier();
            asm volatile("" ::: "memory");

            if (lc == 0){
                #pragma unroll
                for (int ks = 0; ks < 4; ++ks)
                    xxA[ks] = *(const bf16x8*)&s_xx[pair][l15 * 136 + ks * 32 + l4 * 8];
            }

            // W2f8 fragments for this chunk -> regs (before mid-barrier: race-free)
            u64 wf8[4];
            #pragma unroll
            for (int ntl = 0; ntl < 4; ++ntl)
                wf8[ntl] = *(const u64*)&s_w2s[slot][(half * 4 + ntl) * 512 + lane * 8];

            // GEMM1 (bf16, 2 split chains): pre = xx@W1 + base + t*bt -> h (fp8), div
            {
                const float btv = bf2f(s_bt[lc * 32 + half * 16 + l15]);
                f32x4 pa, pb = {0.f, 0.f, 0.f, 0.f};
                pa[0] = upk(base_pk[lc][0], 0) + tcur * btv;
                pa[1] = upk(base_pk[lc][0], 1) + tcur * btv;
                pa[2] = upk(base_pk[lc][1], 0) + tcur * btv;
                pa[3] = upk(base_pk[lc][1], 1) + tcur * btv;
                pa = MFMA16(xxA[0], *(const bf16x8*)&s_w1[slot][(0 * 2 + half) * 512 + lane * 8], pa);
                pb = MFMA16(xxA[1], *(const bf16x8*)&s_w1[slot][(1 * 2 + half) * 512 + lane * 8], pb);
                pa = MFMA16(xxA[2], *(const bf16x8*)&s_w1[slot][(2 * 2 + half) * 512 + lane * 8], pa);
                pb = MFMA16(xxA[3], *(const bf16x8*)&s_w1[slot][(3 * 2 + half) * 512 + lane * 8], pb);
                #pragma unroll
                for (int r = 0; r < 4; ++r){
                    const float h = fast_tanh(pa[r] + pb[r]);
                    divacc[r] += wcur * (1.f - h * h) * upk(q_pk[lc][r >> 1], r & 1);
                    const u32 hb = (u32)__builtin_amdgcn_cvt_pk_fp8_f32(h, h, 0, 0) & 0xffu;
                    s_hh8[pair][(l4 * 4 + r) * 40 + half * 16 + l15] = (unsigned char)hb;
                }
            }
            // mid barrier: h exchanged across pair; slot reads complete everywhere
            asm volatile("s_waitcnt lgkmcnt(0)" ::: "memory");
            __builtin_amdgcn_sched_barrier(0);
            __builtin_amdgcn_s_barrier();
            asm volatile("" ::: "memory");

            // issue chunk c+3 into freed slot (always-issue keeps per-wave vmcnt uniform)
            stage_chunk(slot, (c + 3) & 15);

            // GEMM2 (fp8): dx += h@W2, K=32 slice
            {
                const u64 hf8 = *(const u64*)&s_hh8[pair][l15 * 40 + l4 * 8];
                #pragma unroll
                for (int ntl = 0; ntl < 4; ++ntl)
                    acc[ntl] = MFMAF8((long)hf8, (long)wf8[ntl], acc[ntl]);
            }
        }

        // ---- stage epilogue: RK4 combine (xs in LDS, dxc in regs); write next xx ----
        const float adt = (stg == 2) ? 0.25f : 0.125f;
        #pragma unroll
        for (int ntl = 0; ntl < 4; ++ntl){
            const float b2v = s_b2[half * 64 + ntl * 16 + l15];
            #pragma unroll
            for (int rr = 0; rr < 2; ++rr){
                u32 xp = s_xs[wave][ntl * 2 + rr][lane];
                const float d0 = acc[ntl][2 * rr] + b2v;
                const float d1 = acc[ntl][2 * rr + 1] + b2v;
                const float c0 = upk(dxc_pk[ntl][rr], 0) + wcur * d0;
                const float c1 = upk(dxc_pk[ntl][rr], 1) + wcur * d1;
                const float x00 = upk(xp, 0), x01 = upk(xp, 1);
                float xn0, xn1;
                if (stg < 3){
                    dxc_pk[ntl][rr] = pk2(c0, c1);
                    xn0 = x00 + adt * d0;
                    xn1 = x01 + adt * d1;
                } else {
                    dxc_pk[ntl][rr] = 0u;
                    xn0 = x00 + (0.25f / 6.f) * c0;
                    xn1 = x01 + (0.25f / 6.f) * c1;
                    xp = pk2(xn0, xn1);
                    s_xs[wave][ntl * 2 + rr][lane] = xp;
                }
                const int col = half * 64 + ntl * 16 + l15;
                s_xx[pair][(l4 * 4 + 2 * rr) * 136 + col]     = f2bf(xn0);
                s_xx[pair][(l4 * 4 + 2 * rr + 1) * 136 + col] = f2bf(xn1);
                if (st == 15){
                    y_out[(size_t)(rbase + l4 * 4 + 2 * rr) * 128 + col]     = xn0;
                    y_out[(size_t)(rbase + l4 * 4 + 2 * rr + 1) * 128 + col] = xn1;
                }
                acc[ntl][2 * rr] = 0.f; acc[ntl][2 * rr + 1] = 0.f;
            }
        }
    }

    // ---- logpy: reduce within l15 groups, then across pair halves ----
    #pragma unroll
    for (int r = 0; r < 4; ++r){
        float d = divacc[r];
        d += __shfl_xor(d, 1);
        d += __shfl_xor(d, 2);
        d += __shfl_xor(d, 4);
        d += __shfl_xor(d, 8);
        if (l15 == 0) s_red[pair][half][l4 * 4 + r] = d;
    }
    __syncthreads();
    if (half == 0 && l15 == 0){
        #pragma unroll
        for (int r = 0; r < 4; ++r){
            const int row16 = l4 * 4 + r;
            const int row = rbase + row16;
            lp_out[row] = logpx[row] - (0.25f / 6.f) * (s_red[pair][0][row16] + s_red[pair][1][row16]);
        }
    }
}

extern "C" void kernel_launch(void* const* d_in, const int* in_sizes, int n_in,
                              void* d_out, int out_size, void* d_ws, size_t ws_size,
                              hipStream_t stream) {
    const float* x     = (const float*)d_in[0];
    const float* logpx = (const float*)d_in[1];
    const float* cond  = (const float*)d_in[2];
    const float* e     = (const float*)d_in[3];
    const float* W1    = (const float*)d_in[4];
    const float* Wc    = (const float*)d_in[5];
    const float* bt    = (const float*)d_in[6];
    const float* b1    = (const float*)d_in[7];
    const float* W2    = (const float*)d_in[8];
    const float* b2    = (const float*)d_in[9];

    u16* wp = (u16*)d_ws;                       // 5*65536 u16 = 640 KB
    float* y_out  = (float*)d_out;
    float* lp_out = y_out + (size_t)32768 * 128;

    hipLaunchKernelGGL(pack_weights_kernel, dim3(1280), dim3(256), 0, stream, W1, W2, Wc, wp);
    hipLaunchKernelGGL(cnf_mfma8_kernel, dim3(512), dim3(512), 0, stream,
                       x, logpx, cond, e, b1, wp, bt, b2, y_out, lp_out);
}

// Round 13
// 383.767 us; speedup vs baseline: 1.2586x; 1.2586x over previous
//
#include <hip/hip_runtime.h>

typedef unsigned short u16;
typedef unsigned int   u32;
typedef unsigned long long u64;
typedef __attribute__((ext_vector_type(8))) short bf16x8;
typedef __attribute__((ext_vector_type(4))) float f32x4;

#define MFMA16(A,B,C) __builtin_amdgcn_mfma_f32_16x16x32_bf16(A,B,C,0,0,0)
#define MFMAF8(A,B,C) __builtin_amdgcn_mfma_f32_16x16x32_fp8_fp8(A,B,C,0,0,0)

__device__ __forceinline__ u16 f2bf(float f){
    u32 u = __float_as_uint(f);
    u += 0x7fffu + ((u >> 16) & 1u);
    return (u16)(u >> 16);
}
__device__ __forceinline__ u32 pk2(float lo, float hi){
    return (u32)f2bf(lo) | ((u32)f2bf(hi) << 16);
}
__device__ __forceinline__ float upk(u32 u, int hi){
    return __uint_as_float(hi ? (u & 0xffff0000u) : (u << 16));
}
__device__ __forceinline__ float bf2f(u16 v){
    return __uint_as_float(((u32)v) << 16);
}
__device__ __forceinline__ float fast_tanh(float p){
    float e2 = __expf(2.f * p);
    return 1.f - __fdividef(2.f, e2 + 1.f);
}
__device__ __forceinline__ void gload16(const u16* g, u16* l){
    __builtin_amdgcn_global_load_lds((const __attribute__((address_space(1))) void*)g,
                                     (__attribute__((address_space(3))) void*)l, 16, 0, 0);
}

// ---------------- weight pre-pack kernel (identical to R10/R11, validated) ----------------
// ws (u16 each 65536): [0]=W1 bf16, [1]=unused, [2]=W2 fp8 (64KB bytes, chunked),
//                      [3]=W2T bf16, [4]=Wc bf16
__global__ __launch_bounds__(256) void pack_weights_kernel(
    const float* __restrict__ W1, const float* __restrict__ W2,
    const float* __restrict__ Wc, u16* __restrict__ wp)
{
    int p = blockIdx.x * 256 + threadIdx.x;     // 0 .. 5*65536-1
    int which = p >> 16;
    int q = p & 65535;
    if (which == 1) return;                     // region unused
    if (which == 2){
        int j = q & 7, lane = (q >> 3) & 63;
        int nt = (q >> 9) & 7, lc = (q >> 12) & 15;
        int k = lc * 32 + (lane >> 4) * 8 + j;
        int n = nt * 16 + (lane & 15);
        float v = W2[k * 128 + n];
        u32 b = (u32)__builtin_amdgcn_cvt_pk_fp8_f32(v, 0.f, 0, 0) & 0xffu;
        ((unsigned char*)(wp + 131072))[q] = (unsigned char)b;
        return;
    }
    int j = q & 7, l = (q >> 3) & 63, t = (q >> 9) & 1;
    int ks = (q >> 10) & 3, c = (q >> 12) & 15;
    int l15v = l & 15, l4v = l >> 4;
    int k = 32 * ks + l4v * 8 + j;
    int n = 32 * c + 16 * t + l15v;
    float v = (which == 0) ? W1[k * 512 + n] : (which == 3) ? W2[n * 128 + k] : Wc[k * 512 + n];
    wp[p] = f2bf(v);
}

// ---------------- fused CNF RK4: R11 1-barrier/chunk pipeline, bf16 q, (512,4) ----------------
__global__ __launch_bounds__(512, 4) void cnf_mfma11_kernel(
    const float* __restrict__ x, const float* __restrict__ logpx,
    const float* __restrict__ cond, const float* __restrict__ e,
    const float* __restrict__ b1, const u16* __restrict__ wp,
    const float* __restrict__ bt, const float* __restrict__ b2,
    float* __restrict__ y_out, float* __restrict__ lp_out)
{
    __shared__ __align__(16) u16 s_w1[3][4096];               // 24KB W1 stream slots
    __shared__ __align__(16) unsigned char s_w2s[4][4096];    // 16KB W2-fp8 stream slots
    __shared__ __align__(16) u16 s_xx[4][16 * 136];           // 17KB per-pair xx transpose
    __shared__ __align__(16) unsigned char s_hh8[4][2][16 * 40]; // 5KB per-pair h fp8, dbuf
    __shared__ u16 s_bt[512];
    __shared__ float s_b2[128];
    __shared__ float s_red[4][2][16];

    const int tid = threadIdx.x, wave = tid >> 6, lane = tid & 63;
    const int l15 = lane & 15, l4 = lane >> 4;
    const int pair = wave >> 1, half = wave & 1;
    const int rbase = blockIdx.x * 64 + pair * 16;
    const int wlt4 = __builtin_amdgcn_readfirstlane((wave < 4) ? 1 : 0);

    const u16* W1p  = wp;
    const u16* W2Tp = wp + 196608;
    const u16* Wcp  = wp + 262144;
    const unsigned char* W2f8p = (const unsigned char*)(wp + 131072);

    auto stage_chunk = [&](int slot, int slot4, int cidx){
        gload16(W1p + cidx * 4096 + wave * 512 + lane * 8, &s_w1[slot][wave * 512 + lane * 8]);
        if (wave < 4)
            gload16((const u16*)(W2f8p + cidx * 4096 + wave * 1024 + lane * 16),
                    (u16*)&s_w2s[slot4][wave * 1024 + lane * 16]);
    };

    s_bt[tid] = f2bf(bt[tid]);
    if (tid < 128) s_b2[tid] = b2[tid];

    u32 base_pk[16][2], q_pk[16][2];

    // ---- cond transpose -> cA frags; pass 1: base = cond@Wc + b1 ----
    {
        #pragma unroll
        for (int i = 0; i < 8; ++i){
            const int row = half * 8 + i;
            s_xx[pair][row * 136 + lane]      = f2bf(cond[(size_t)(rbase + row) * 128 + lane]);
            s_xx[pair][row * 136 + 64 + lane] = f2bf(cond[(size_t)(rbase + row) * 128 + 64 + lane]);
        }
        __syncthreads();
        bf16x8 cA[4];
        #pragma unroll
        for (int ks = 0; ks < 4; ++ks)
            cA[ks] = *(const bf16x8*)&s_xx[pair][l15 * 136 + ks * 32 + l4 * 8];
        __syncthreads();

        #pragma unroll 1
        for (int nc = 0; nc < 16; ++nc){
            gload16(Wcp + nc * 4096 + wave * 512 + lane * 8, &s_w1[0][wave * 512 + lane * 8]);
            __syncthreads();                     // drains vmcnt -> chunk landed
            f32x4 ab = {0.f, 0.f, 0.f, 0.f};
            #pragma unroll
            for (int ks = 0; ks < 4; ++ks)
                ab = MFMA16(cA[ks], *(const bf16x8*)&s_w1[0][(ks * 2 + half) * 512 + lane * 8], ab);
            const float b1v = b1[nc * 32 + half * 16 + l15];
            base_pk[nc][0] = pk2(ab[0] + b1v, ab[1] + b1v);
            base_pk[nc][1] = pk2(ab[2] + b1v, ab[3] + b1v);
            __syncthreads();                     // reads drained before next overwrite
        }
    }

    // ---- e transpose -> eA frags; pass 2: q = (e@W1) ⊙ (e@W2T), packed bf16 ----
    {
        #pragma unroll
        for (int i = 0; i < 8; ++i){
            const int row = half * 8 + i;
            s_xx[pair][row * 136 + lane]      = f2bf(e[(size_t)(rbase + row) * 128 + lane]);
            s_xx[pair][row * 136 + 64 + lane] = f2bf(e[(size_t)(rbase + row) * 128 + 64 + lane]);
        }
        __syncthreads();
        bf16x8 eA[4];
        #pragma unroll
        for (int ks = 0; ks < 4; ++ks)
            eA[ks] = *(const bf16x8*)&s_xx[pair][l15 * 136 + ks * 32 + l4 * 8];
        __syncthreads();

        #pragma unroll 1
        for (int nc = 0; nc < 16; ++nc){
            gload16(W1p  + nc * 4096 + wave * 512 + lane * 8, &s_w1[0][wave * 512 + lane * 8]);
            gload16(W2Tp + nc * 4096 + wave * 512 + lane * 8, &s_w1[1][wave * 512 + lane * 8]);
            __syncthreads();
            f32x4 ew = {0.f,0.f,0.f,0.f}, e2 = {0.f,0.f,0.f,0.f};
            #pragma unroll
            for (int ks = 0; ks < 4; ++ks){
                ew = MFMA16(eA[ks], *(const bf16x8*)&s_w1[0][(ks * 2 + half) * 512 + lane * 8], ew);
                e2 = MFMA16(eA[ks], *(const bf16x8*)&s_w1[1][(ks * 2 + half) * 512 + lane * 8], e2);
            }
            q_pk[nc][0] = pk2(ew[0] * e2[0], ew[1] * e2[1]);
            q_pk[nc][1] = pk2(ew[2] * e2[2], ew[3] * e2[3]);
            __syncthreads();
        }
    }

    // ---- x0 init: xs in regs; bf16 copy into pair xx area ----
    u32 xs_pk[4][2];
    #pragma unroll
    for (int ntl = 0; ntl < 4; ++ntl)
        #pragma unroll
        for (int rr = 0; rr < 2; ++rr){
            const int row0 = rbase + l4 * 4 + 2 * rr;
            const int col = half * 64 + ntl * 16 + l15;
            const float a0 = x[(size_t)row0 * 128 + col];
            const float a1 = x[(size_t)(row0 + 1) * 128 + col];
            xs_pk[ntl][rr] = pk2(a0, a1);
            s_xx[pair][(l4 * 4 + 2 * rr) * 136 + col]     = (u16)(xs_pk[ntl][rr] & 0xffffu);
            s_xx[pair][(l4 * 4 + 2 * rr + 1) * 136 + col] = (u16)(xs_pk[ntl][rr] >> 16);
        }

    // ---- prime pipeline: chunks 0,1,2; drain L(0), keep L(1),L(2) in flight ----
    #pragma unroll
    for (int c = 0; c < 3; ++c) stage_chunk(c, c, c);
    if (wlt4) { asm volatile("s_waitcnt vmcnt(4) lgkmcnt(0)" ::: "memory"); }
    else      { asm volatile("s_waitcnt vmcnt(2) lgkmcnt(0)" ::: "memory"); }
    __builtin_amdgcn_sched_barrier(0);
    __builtin_amdgcn_s_barrier();
    asm volatile("" ::: "memory");

    // ---- main RK4 loop: 16 stages x 16 chunks, ONE barrier per chunk ----
    f32x4 acc[4];
    u32 dxc_pk[4][2];
    float divacc[4] = {0.f, 0.f, 0.f, 0.f};
    #pragma unroll
    for (int ntl = 0; ntl < 4; ++ntl){
        acc[ntl] = {0.f, 0.f, 0.f, 0.f};
        dxc_pk[ntl][0] = 0u; dxc_pk[ntl][1] = 0u;
    }

    #pragma unroll 1
    for (int st = 0; st < 16; ++st){
        const int stg = st & 3;
        const float tcur = 0.25f * (float)(st >> 2) + ((stg == 0) ? 0.f : (stg == 3) ? 0.25f : 0.125f);
        const float wcur = (stg == 1 || stg == 2) ? 2.f : 1.f;

        #pragma unroll 1
        for (int lc = 0; lc < 16; ++lc){
            const int c = st * 16 + lc;
            const int slot = c % 3;

            // GEMM1 (bf16): pre = xx@W1 + base + t*bt -> h (fp8, dbuf), div
            {
                const float btv = bf2f(s_bt[lc * 32 + half * 16 + l15]);
                f32x4 pa, pb = {0.f, 0.f, 0.f, 0.f};
                pa[0] = upk(base_pk[lc][0], 0) + tcur * btv;
                pa[1] = upk(base_pk[lc][0], 1) + tcur * btv;
                pa[2] = upk(base_pk[lc][1], 0) + tcur * btv;
                pa[3] = upk(base_pk[lc][1], 1) + tcur * btv;
                bf16x8 xxA0 = *(const bf16x8*)&s_xx[pair][l15 * 136 +  0 + l4 * 8];
                bf16x8 xxA1 = *(const bf16x8*)&s_xx[pair][l15 * 136 + 32 + l4 * 8];
                bf16x8 xxA2 = *(const bf16x8*)&s_xx[pair][l15 * 136 + 64 + l4 * 8];
                bf16x8 xxA3 = *(const bf16x8*)&s_xx[pair][l15 * 136 + 96 + l4 * 8];
                pa = MFMA16(xxA0, *(const bf16x8*)&s_w1[slot][(0 * 2 + half) * 512 + lane * 8], pa);
                pb = MFMA16(xxA1, *(const bf16x8*)&s_w1[slot][(1 * 2 + half) * 512 + lane * 8], pb);
                pa = MFMA16(xxA2, *(const bf16x8*)&s_w1[slot][(2 * 2 + half) * 512 + lane * 8], pa);
                pb = MFMA16(xxA3, *(const bf16x8*)&s_w1[slot][(3 * 2 + half) * 512 + lane * 8], pb);
                #pragma unroll
                for (int r = 0; r < 4; ++r){
                    const float h = fast_tanh(pa[r] + pb[r]);
                    divacc[r] += wcur * (1.f - h * h) * upk(q_pk[lc][r >> 1], r & 1);
                    const u32 hb = (u32)__builtin_amdgcn_cvt_pk_fp8_f32(h, h, 0, 0) & 0xffu;
                    s_hh8[pair][c & 1][(l4 * 4 + r) * 40 + half * 16 + l15] = (unsigned char)hb;
                }
            }

            // single per-chunk sync: own loads for chunk c+1 landed; LDS ops retired
            if (wlt4) { asm volatile("s_waitcnt vmcnt(2) lgkmcnt(0)" ::: "memory"); }
            else      { asm volatile("s_waitcnt vmcnt(1) lgkmcnt(0)" ::: "memory"); }
            __builtin_amdgcn_sched_barrier(0);
            __builtin_amdgcn_s_barrier();
            asm volatile("" ::: "memory");

            // issue chunk c+3 (always-issue keeps per-wave vmcnt uniform)
            stage_chunk((c + 3) % 3, (c + 3) & 3, (c + 3) & 15);

            // GEMM2 (fp8): dx += h@W2, K=32 slice, B-frags direct from LDS
            {
                const u64 hf8 = *(const u64*)&s_hh8[pair][c & 1][l15 * 40 + l4 * 8];
                #pragma unroll
                for (int ntl = 0; ntl < 4; ++ntl){
                    const u64 wf8 = *(const u64*)&s_w2s[c & 3][(half * 4 + ntl) * 512 + lane * 8];
                    acc[ntl] = MFMAF8((long)hf8, (long)wf8, acc[ntl]);
                }
            }
        }

        // ---- stage epilogue: RK4 combine in regs; write next xx ----
        const float adt = (stg == 2) ? 0.25f : 0.125f;
        #pragma unroll
        for (int ntl = 0; ntl < 4; ++ntl){
            const float b2v = s_b2[half * 64 + ntl * 16 + l15];
            #pragma unroll
            for (int rr = 0; rr < 2; ++rr){
                const float d0 = acc[ntl][2 * rr] + b2v;
                const float d1 = acc[ntl][2 * rr + 1] + b2v;
                const float c0 = upk(dxc_pk[ntl][rr], 0) + wcur * d0;
                const float c1 = upk(dxc_pk[ntl][rr], 1) + wcur * d1;
                const float x00 = upk(xs_pk[ntl][rr], 0);
                const float x01 = upk(xs_pk[ntl][rr], 1);
                float xn0, xn1;
                if (stg < 3){
                    dxc_pk[ntl][rr] = pk2(c0, c1);
                    xn0 = x00 + adt * d0;
                    xn1 = x01 + adt * d1;
                } else {
                    dxc_pk[ntl][rr] = 0u;
                    xn0 = x00 + (0.25f / 6.f) * c0;
                    xn1 = x01 + (0.25f / 6.f) * c1;
                    xs_pk[ntl][rr] = pk2(xn0, xn1);
                }
                const int col = half * 64 + ntl * 16 + l15;
                s_xx[pair][(l4 * 4 + 2 * rr) * 136 + col]     = f2bf(xn0);
                s_xx[pair][(l4 * 4 + 2 * rr + 1) * 136 + col] = f2bf(xn1);
                if (st == 15){
                    y_out[(size_t)(rbase + l4 * 4 + 2 * rr) * 128 + col]     = xn0;
                    y_out[(size_t)(rbase + l4 * 4 + 2 * rr + 1) * 128 + col] = xn1;
                }
                acc[ntl][2 * rr] = 0.f; acc[ntl][2 * rr + 1] = 0.f;
            }
        }

        // stage-end: xn visible to partner before next stage's GEMM1 reads
        asm volatile("s_waitcnt lgkmcnt(0)" ::: "memory");
        __builtin_amdgcn_sched_barrier(0);
        __builtin_amdgcn_s_barrier();
        asm volatile("" ::: "memory");
    }

    // ---- logpy: reduce within l15 groups, then across pair halves ----
    #pragma unroll
    for (int r = 0; r < 4; ++r){
        float d = divacc[r];
        d += __shfl_xor(d, 1);
        d += __shfl_xor(d, 2);
        d += __shfl_xor(d, 4);
        d += __shfl_xor(d, 8);
        if (l15 == 0) s_red[pair][half][l4 * 4 + r] = d;
    }
    __syncthreads();
    if (half == 0 && l15 == 0){
        #pragma unroll
        for (int r = 0; r < 4; ++r){
            const int row16 = l4 * 4 + r;
            const int row = rbase + row16;
            lp_out[row] = logpx[row] - (0.25f / 6.f) * (s_red[pair][0][row16] + s_red[pair][1][row16]);
        }
    }
}

extern "C" void kernel_launch(void* const* d_in, const int* in_sizes, int n_in,
                              void* d_out, int out_size, void* d_ws, size_t ws_size,
                              hipStream_t stream) {
    const float* x     = (const float*)d_in[0];
    const float* logpx = (const float*)d_in[1];
    const float* cond  = (const float*)d_in[2];
    const float* e     = (const float*)d_in[3];
    const float* W1    = (const float*)d_in[4];
    const float* Wc    = (const float*)d_in[5];
    const float* bt    = (const float*)d_in[6];
    const float* b1    = (const float*)d_in[7];
    const float* W2    = (const float*)d_in[8];
    const float* b2    = (const float*)d_in[9];

    u16* wp = (u16*)d_ws;                       // 5*65536 u16 = 640 KB
    float* y_out  = (float*)d_out;
    float* lp_out = y_out + (size_t)32768 * 128;

    hipLaunchKernelGGL(pack_weights_kernel, dim3(1280), dim3(256), 0, stream, W1, W2, Wc, wp);
    hipLaunchKernelGGL(cnf_mfma11_kernel, dim3(512), dim3(512), 0, stream,
                       x, logpx, cond, e, b1, wp, bt, b2, y_out, lp_out);
}

// Round 15
// 380.738 us; speedup vs baseline: 1.2686x; 1.0080x over previous
//
#include <hip/hip_runtime.h>

typedef unsigned short u16;
typedef unsigned int   u32;
typedef unsigned long long u64;
typedef unsigned char  u8;
typedef __attribute__((ext_vector_type(8))) short bf16x8;
typedef __attribute__((ext_vector_type(4))) float f32x4;

#define MFMA16(A,B,C) __builtin_amdgcn_mfma_f32_16x16x32_bf16(A,B,C,0,0,0)
#define MFMAF8(A,B,C) __builtin_amdgcn_mfma_f32_16x16x32_fp8_fp8(A,B,C,0,0,0)

__device__ __forceinline__ u16 f2bf(float f){
    u32 u = __float_as_uint(f);
    u += 0x7fffu + ((u >> 16) & 1u);
    return (u16)(u >> 16);
}
__device__ __forceinline__ u32 pk2(float lo, float hi){
    return (u32)f2bf(lo) | ((u32)f2bf(hi) << 16);
}
__device__ __forceinline__ float upk(u32 u, int hi){
    return __uint_as_float(hi ? (u & 0xffff0000u) : (u << 16));
}
__device__ __forceinline__ float bf2f(u16 v){
    return __uint_as_float(((u32)v) << 16);
}
__device__ __forceinline__ float fast_tanh(float p){
    float e2 = __expf(2.f * p);
    return 1.f - __fdividef(2.f, e2 + 1.f);
}
__device__ __forceinline__ void gload16(const u16* g, u16* l){
    __builtin_amdgcn_global_load_lds((const __attribute__((address_space(1))) void*)g,
                                     (__attribute__((address_space(3))) void*)l, 16, 0, 0);
}

// ---------------- weight pre-pack kernel ----------------
// ws layout (u16 offsets), 64-col chunks (8 chunks per matrix):
//  [0,65536)      W1  bf16: chunk c: q = ks(2b)|t(2b)|l(6b)|j(3b)
//                 k = 32ks+(l>>4)*8+j ; n = 64c+16t+(l&15) ; val = W1[k*512+n]
//  [65536,131072) W2T bf16: same geometry ; val = W2[n*128+k]  (n=H-col, k=D)
//  [131072,196608) Wc bf16: same geometry ; val = Wc[k*512+n]
//  [196608,229376) W2 fp8, 65536 BYTES: chunk c (64 h-rows): byte q =
//                 ksl(1b)|nt(3b)|lane(6b)|j(3b)
//                 k_h = 64c+32ksl+(lane>>4)*8+j ; n_d = 16nt+(lane&15)
__global__ __launch_bounds__(256) void pack_weights_kernel(
    const float* __restrict__ W1, const float* __restrict__ W2,
    const float* __restrict__ Wc, u16* __restrict__ wp)
{
    int p = blockIdx.x * 256 + threadIdx.x;     // 0 .. 262143
    if (p < 196608){
        int which = p >> 16;                    // 0=W1, 1=W2T, 2=Wc
        int q = p & 65535;
        int c = q >> 13, w = q & 8191;
        int j = w & 7, l = (w >> 3) & 63, t = (w >> 9) & 3, ks = (w >> 11) & 3;
        int k = 32 * ks + (l >> 4) * 8 + j;
        int n = 64 * c + 16 * t + (l & 15);
        float v = (which == 0) ? W1[k * 512 + n]
                : (which == 1) ? W2[n * 128 + k]
                :                Wc[k * 512 + n];
        wp[p] = f2bf(v);
    } else {
        int q = p - 196608;                     // byte index 0..65535
        int c = q >> 13, w = q & 8191;
        int j = w & 7, lane = (w >> 3) & 63, nt = (w >> 9) & 7, ksl = (w >> 12) & 1;
        int kh = 64 * c + 32 * ksl + (lane >> 4) * 8 + j;
        int nd = 16 * nt + (lane & 15);
        float v = W2[kh * 128 + nd];
        u32 b = (u32)__builtin_amdgcn_cvt_pk_fp8_f32(v, 0.f, 0, 0) & 0xffu;
        ((u8*)(wp + 196608))[q] = (u8)b;
    }
}

// ---------------- fused CNF RK4: quad-split (4 waves / 16 rows), 64-col chunks ----------------
__global__ __launch_bounds__(512, 4) void cnf_mfma12_kernel(
    const float* __restrict__ x, const float* __restrict__ logpx,
    const float* __restrict__ cond, const float* __restrict__ e,
    const float* __restrict__ b1, const u16* __restrict__ wp,
    const float* __restrict__ bt, const float* __restrict__ b2,
    float* __restrict__ y_out, float* __restrict__ lp_out)
{
    __shared__ __align__(16) u16 s_w1[2][8192];        // 32KB W1 stream slots (16KB chunks)
    __shared__ __align__(16) u8  s_w2[2][8192];        // 16KB W2-fp8 stream slots
    __shared__ __align__(16) u16 s_xx[2][16 * 132];    // 8.25KB per-group xx transpose
    __shared__ __align__(16) u8  s_hh8[2][2][16 * 72]; // 4.5KB per-group h fp8, dbuf
    __shared__ u16 s_bt[512];
    __shared__ float s_b2[128];
    __shared__ float s_red[2][4][16];

    const int tid = threadIdx.x, wave = tid >> 6, lane = tid & 63;
    const int l15 = lane & 15, l4 = lane >> 4;
    const int g = wave >> 2, wq = wave & 3;            // group, quad-position
    const int gtid = tid & 255;
    const int rbase = blockIdx.x * 32 + g * 16;

    const u16* W1p  = wp;
    const u16* W2Tp = wp + 65536;
    const u16* Wcp  = wp + 131072;
    const u8*  W2f8p = (const u8*)(wp + 196608);

    auto stage_chunk = [&](int cidx){
        const int slot = cidx & 1;
        const u16* src = W1p + cidx * 8192 + tid * 8;
        gload16(src,        &s_w1[slot][tid * 8]);
        gload16(src + 4096, &s_w1[slot][4096 + tid * 8]);
        gload16((const u16*)(W2f8p + cidx * 8192 + tid * 16), (u16*)&s_w2[slot][tid * 16]);
    };

    s_bt[tid] = f2bf(bt[tid]);
    if (tid < 128) s_b2[tid] = b2[tid];

    u32 base_pk[8][2], q_pk[8][2];

    // ---- cond transpose -> cA frags; pass 1: base = cond@Wc + b1 ----
    {
        #pragma unroll
        for (int i = 0; i < 8; ++i){
            const int elem = i * 256 + gtid;           // 0..2047
            const int row = elem >> 7, col = elem & 127;
            s_xx[g][row * 132 + col] = f2bf(cond[(size_t)(rbase + row) * 128 + col]);
        }
        __syncthreads();
        bf16x8 cA[4];
        #pragma unroll
        for (int ks = 0; ks < 4; ++ks)
            cA[ks] = *(const bf16x8*)&s_xx[g][l15 * 132 + ks * 32 + l4 * 8];
        __syncthreads();

        #pragma unroll 1
        for (int nc = 0; nc < 8; ++nc){
            const u16* src = Wcp + nc * 8192 + tid * 8;
            gload16(src,        &s_w1[0][tid * 8]);
            gload16(src + 4096, &s_w1[0][4096 + tid * 8]);
            __syncthreads();
            f32x4 ab = {0.f, 0.f, 0.f, 0.f};
            #pragma unroll
            for (int ks = 0; ks < 4; ++ks)
                ab = MFMA16(cA[ks], *(const bf16x8*)&s_w1[0][(ks * 4 + wq) * 512 + lane * 8], ab);
            const float b1v = b1[nc * 64 + wq * 16 + l15];
            base_pk[nc][0] = pk2(ab[0] + b1v, ab[1] + b1v);
            base_pk[nc][1] = pk2(ab[2] + b1v, ab[3] + b1v);
            __syncthreads();
        }
    }

    // ---- e transpose -> eA frags; pass 2: q = (e@W1) ⊙ (e@W2T), packed bf16 ----
    {
        #pragma unroll
        for (int i = 0; i < 8; ++i){
            const int elem = i * 256 + gtid;
            const int row = elem >> 7, col = elem & 127;
            s_xx[g][row * 132 + col] = f2bf(e[(size_t)(rbase + row) * 128 + col]);
        }
        __syncthreads();
        bf16x8 eA[4];
        #pragma unroll
        for (int ks = 0; ks < 4; ++ks)
            eA[ks] = *(const bf16x8*)&s_xx[g][l15 * 132 + ks * 32 + l4 * 8];
        __syncthreads();

        #pragma unroll 1
        for (int nc = 0; nc < 8; ++nc){
            const u16* s1 = W1p  + nc * 8192 + tid * 8;
            const u16* s2 = W2Tp + nc * 8192 + tid * 8;
            gload16(s1,        &s_w1[0][tid * 8]);
            gload16(s1 + 4096, &s_w1[0][4096 + tid * 8]);
            gload16(s2,        &s_w1[1][tid * 8]);
            gload16(s2 + 4096, &s_w1[1][4096 + tid * 8]);
            __syncthreads();
            f32x4 ew = {0.f,0.f,0.f,0.f}, e2 = {0.f,0.f,0.f,0.f};
            #pragma unroll
            for (int ks = 0; ks < 4; ++ks){
                ew = MFMA16(eA[ks], *(const bf16x8*)&s_w1[0][(ks * 4 + wq) * 512 + lane * 8], ew);
                e2 = MFMA16(eA[ks], *(const bf16x8*)&s_w1[1][(ks * 4 + wq) * 512 + lane * 8], e2);
            }
            q_pk[nc][0] = pk2(ew[0] * e2[0], ew[1] * e2[1]);
            q_pk[nc][1] = pk2(ew[2] * e2[2], ew[3] * e2[3]);
            __syncthreads();
        }
    }

    // ---- x0 init: xs in regs (wave owns D-cols wq*32..wq*32+31); bf16 copy to s_xx ----
    u32 xs_pk[2][2];
    #pragma unroll
    for (int ntl = 0; ntl < 2; ++ntl)
        #pragma unroll
        for (int rr = 0; rr < 2; ++rr){
            const int row0 = rbase + l4 * 4 + 2 * rr;
            const int col = wq * 32 + ntl * 16 + l15;
            const float a0 = x[(size_t)row0 * 128 + col];
            const float a1 = x[(size_t)(row0 + 1) * 128 + col];
            xs_pk[ntl][rr] = pk2(a0, a1);
            s_xx[g][(l4 * 4 + 2 * rr) * 132 + col]     = (u16)(xs_pk[ntl][rr] & 0xffffu);
            s_xx[g][(l4 * 4 + 2 * rr + 1) * 132 + col] = (u16)(xs_pk[ntl][rr] >> 16);
        }

    // ---- prime pipeline: chunks 0,1; drain chunk 0's 3 loads, keep chunk 1 in flight ----
    stage_chunk(0);
    stage_chunk(1);
    asm volatile("s_waitcnt vmcnt(3) lgkmcnt(0)" ::: "memory");
    __builtin_amdgcn_sched_barrier(0);
    __builtin_amdgcn_s_barrier();
    asm volatile("" ::: "memory");

    // ---- main RK4 loop: 16 stages x 8 chunks of 64 H-cols ----
    f32x4 acc[2];
    u32 dxc_pk[2][2];
    float divacc[4] = {0.f, 0.f, 0.f, 0.f};
    #pragma unroll
    for (int ntl = 0; ntl < 2; ++ntl){
        acc[ntl] = {0.f, 0.f, 0.f, 0.f};
        dxc_pk[ntl][0] = 0u; dxc_pk[ntl][1] = 0u;
    }

    #pragma unroll 1
    for (int st = 0; st < 16; ++st){
        const int stg = st & 3;
        const float tcur = 0.25f * (float)(st >> 2) + ((stg == 0) ? 0.f : (stg == 3) ? 0.25f : 0.125f);
        const float wcur = (stg == 1 || stg == 2) ? 2.f : 1.f;

        #pragma unroll 1
        for (int lc = 0; lc < 8; ++lc){
            const int c = st * 8 + lc;
            const int slot = c & 1;
            u64 wf8[2][2];

            // GEMM1 (bf16): pre = xx@W1 + base + t*bt -> h (fp8, dbuf), div
            {
                const float btv = bf2f(s_bt[lc * 64 + wq * 16 + l15]);
                f32x4 pa, pb = {0.f, 0.f, 0.f, 0.f};
                pa[0] = upk(base_pk[lc][0], 0) + tcur * btv;
                pa[1] = upk(base_pk[lc][0], 1) + tcur * btv;
                pa[2] = upk(base_pk[lc][1], 0) + tcur * btv;
                pa[3] = upk(base_pk[lc][1], 1) + tcur * btv;
                bf16x8 xxA0 = *(const bf16x8*)&s_xx[g][l15 * 132 +  0 + l4 * 8];
                bf16x8 xxA1 = *(const bf16x8*)&s_xx[g][l15 * 132 + 32 + l4 * 8];
                bf16x8 xxA2 = *(const bf16x8*)&s_xx[g][l15 * 132 + 64 + l4 * 8];
                bf16x8 xxA3 = *(const bf16x8*)&s_xx[g][l15 * 132 + 96 + l4 * 8];
                pa = MFMA16(xxA0, *(const bf16x8*)&s_w1[slot][(0 * 4 + wq) * 512 + lane * 8], pa);
                pb = MFMA16(xxA1, *(const bf16x8*)&s_w1[slot][(1 * 4 + wq) * 512 + lane * 8], pb);
                pa = MFMA16(xxA2, *(const bf16x8*)&s_w1[slot][(2 * 4 + wq) * 512 + lane * 8], pa);
                pb = MFMA16(xxA3, *(const bf16x8*)&s_w1[slot][(3 * 4 + wq) * 512 + lane * 8], pb);

                // preload W2f8 fragments to regs BEFORE the barrier (slot is reused by issue below)
                #pragma unroll
                for (int ksl = 0; ksl < 2; ++ksl)
                    #pragma unroll
                    for (int ntl = 0; ntl < 2; ++ntl)
                        wf8[ksl][ntl] = *(const u64*)&s_w2[slot][(ksl * 8 + wq * 2 + ntl) * 512 + lane * 8];

                #pragma unroll
                for (int r = 0; r < 4; ++r){
                    const float h = fast_tanh(pa[r] + pb[r]);
                    divacc[r] += wcur * (1.f - h * h) * upk(q_pk[lc][r >> 1], r & 1);
                    const u32 hb = (u32)__builtin_amdgcn_cvt_pk_fp8_f32(h, h, 0, 0) & 0xffu;
                    s_hh8[g][c & 1][(l4 * 4 + r) * 72 + wq * 16 + l15] = (u8)hb;
                }
            }

            // single per-chunk sync: chunk c+1's 3 loads landed; all LDS ops retired
            asm volatile("s_waitcnt vmcnt(0) lgkmcnt(0)" ::: "memory");
            __builtin_amdgcn_sched_barrier(0);
            __builtin_amdgcn_s_barrier();
            asm volatile("" ::: "memory");

            // issue chunk c+2 (wrap within the 8-chunk matrix; parity preserved)
            stage_chunk((c + 2) & 7);

            // GEMM2 (fp8): dx += h@W2 over this chunk's K=64 (2 K-slices)
            #pragma unroll
            for (int ksl = 0; ksl < 2; ++ksl){
                const u64 hf8 = *(const u64*)&s_hh8[g][c & 1][l15 * 72 + ksl * 32 + l4 * 8];
                #pragma unroll
                for (int ntl = 0; ntl < 2; ++ntl)
                    acc[ntl] = MFMAF8((long)hf8, (long)wf8[ksl][ntl], acc[ntl]);
            }
        }

        // ---- stage epilogue: RK4 combine in regs; write next xx ----
        const float adt = (stg == 2) ? 0.25f : 0.125f;
        #pragma unroll
        for (int ntl = 0; ntl < 2; ++ntl){
            const float b2v = s_b2[wq * 32 + ntl * 16 + l15];
            #pragma unroll
            for (int rr = 0; rr < 2; ++rr){
                const float d0 = acc[ntl][2 * rr] + b2v;
                const float d1 = acc[ntl][2 * rr + 1] + b2v;
                const float c0 = upk(dxc_pk[ntl][rr], 0) + wcur * d0;
                const float c1 = upk(dxc_pk[ntl][rr], 1) + wcur * d1;
                const float x00 = upk(xs_pk[ntl][rr], 0);
                const float x01 = upk(xs_pk[ntl][rr], 1);
                float xn0, xn1;
                if (stg < 3){
                    dxc_pk[ntl][rr] = pk2(c0, c1);
                    xn0 = x00 + adt * d0;
                    xn1 = x01 + adt * d1;
                } else {
                    dxc_pk[ntl][rr] = 0u;
                    xn0 = x00 + (0.25f / 6.f) * c0;
                    xn1 = x01 + (0.25f / 6.f) * c1;
                    xs_pk[ntl][rr] = pk2(xn0, xn1);
                }
                const int col = wq * 32 + ntl * 16 + l15;
                s_xx[g][(l4 * 4 + 2 * rr) * 132 + col]     = f2bf(xn0);
                s_xx[g][(l4 * 4 + 2 * rr + 1) * 132 + col] = f2bf(xn1);
                if (st == 15){
                    y_out[(size_t)(rbase + l4 * 4 + 2 * rr) * 128 + col]     = xn0;
                    y_out[(size_t)(rbase + l4 * 4 + 2 * rr + 1) * 128 + col] = xn1;
                }
                acc[ntl][2 * rr] = 0.f; acc[ntl][2 * rr + 1] = 0.f;
            }
        }

        // stage-end: xn visible to group before next stage's GEMM1 reads
        asm volatile("s_waitcnt lgkmcnt(0)" ::: "memory");
        __builtin_amdgcn_sched_barrier(0);
        __builtin_amdgcn_s_barrier();
        asm volatile("" ::: "memory");
    }

    // ---- logpy: reduce within l15 groups, then across the 4 quad waves ----
    #pragma unroll
    for (int r = 0; r < 4; ++r){
        float d = divacc[r];
        d += __shfl_xor(d, 1);
        d += __shfl_xor(d, 2);
        d += __shfl_xor(d, 4);
        d += __shfl_xor(d, 8);
        if (l15 == 0) s_red[g][wq][l4 * 4 + r] = d;
    }
    __syncthreads();
    if (wq == 0 && l15 == 0){
        #pragma unroll
        for (int r = 0; r < 4; ++r){
            const int row16 = l4 * 4 + r;
            const int row = rbase + row16;
            const float s = s_red[g][0][row16] + s_red[g][1][row16]
                          + s_red[g][2][row16] + s_red[g][3][row16];
            lp_out[row] = logpx[row] - (0.25f / 6.f) * s;
        }
    }
}

extern "C" void kernel_launch(void* const* d_in, const int* in_sizes, int n_in,
                              void* d_out, int out_size, void* d_ws, size_t ws_size,
                              hipStream_t stream) {
    const float* x     = (const float*)d_in[0];
    const float* logpx = (const float*)d_in[1];
    const float* cond  = (const float*)d_in[2];
    const float* e     = (const float*)d_in[3];
    const float* W1    = (const float*)d_in[4];
    const float* Wc    = (const float*)d_in[5];
    const float* bt    = (const float*)d_in[6];
    const float* b1    = (const float*)d_in[7];
    const float* W2    = (const float*)d_in[8];
    const float* b2    = (const float*)d_in[9];

    u16* wp = (u16*)d_ws;                       // 229376 u16 = 448 KB used
    float* y_out  = (float*)d_out;
    float* lp_out = y_out + (size_t)32768 * 128;

    hipLaunchKernelGGL(pack_weights_kernel, dim3(1024), dim3(256), 0, stream, W1, W2, Wc, wp);
    hipLaunchKernelGGL(cnf_mfma12_kernel, dim3(1024), dim3(512), 0, stream,
                       x, logpx, cond, e, b1, wp, bt, b2, y_out, lp_out);
}